// Round 1
// baseline (1112.410 us; speedup 1.0000x reference)
//
#include <hip/hip_runtime.h>

#define N_TOK 8192
#define DIM   1024
#define FFN   4096
#define NEXP  8
#define TOPK  2
#define NENT  (N_TOK * TOPK)   // 16384
#define MAXMT 10               // max 256-row m-tiles per expert (cnt<=2560; mean 2048, sigma 42)

using short8  = __attribute__((ext_vector_type(8))) short;
using floatx4 = __attribute__((ext_vector_type(4))) float;

__device__ __forceinline__ unsigned short f2bf(float f) {
    union { float f; unsigned u; } v; v.f = f;
    unsigned r = v.u + 0x7fffu + ((v.u >> 16) & 1u);   // round-to-nearest-even
    return (unsigned short)(r >> 16);
}

__device__ __forceinline__ float bf2f(unsigned short s) {
    union { unsigned u; float f; } v; v.u = ((unsigned)s) << 16;
    return v.f;
}

#define GLOAD_LDS16(gptr, lptr) __builtin_amdgcn_global_load_lds( \
    (__attribute__((address_space(1))) void*)(void*)(gptr),       \
    (__attribute__((address_space(3))) void*)(lptr), 16, 0, 0)

#define BARRIER() asm volatile("s_barrier" ::: "memory")
#define WAITV6()  asm volatile("s_waitcnt vmcnt(6)" ::: "memory")
#define WAITV0()  asm volatile("s_waitcnt vmcnt(0)" ::: "memory")
#define SCHED0()  __builtin_amdgcn_sched_barrier(0)

// ---------------- conversion kernels ----------------

__global__ __launch_bounds__(256) void cvt_x_kernel(const float4* __restrict__ in,
                                                    ushort4* __restrict__ out) {
    int i = blockIdx.x * 256 + threadIdx.x;   // grid sized exactly
    float4 v = in[i];
    ushort4 o;
    o.x = f2bf(v.x); o.y = f2bf(v.y); o.z = f2bf(v.z); o.w = f2bf(v.w);
    out[i] = o;
}

// in: [E][R][C] f32 -> out: [E][C][R] bf16; 64x64 tiles, ushort4 writes
__global__ __launch_bounds__(256) void transpose_cvt(const float* __restrict__ in,
                                                     unsigned short* __restrict__ out,
                                                     int R, int C) {
    __shared__ float tile[64][65];
    int e  = blockIdx.z;
    int c0 = blockIdx.x * 64;
    int r0 = blockIdx.y * 64;
    const float* inp = in + (size_t)e * R * C;
    unsigned short* outp = out + (size_t)e * R * C;
    int tid = threadIdx.x;
    int lrow = tid >> 6, lcol = tid & 63;
#pragma unroll
    for (int i = 0; i < 16; i++) {
        int r = i * 4 + lrow;
        tile[r][lcol] = inp[(size_t)(r0 + r) * C + c0 + lcol];
    }
    __syncthreads();
    int r4 = (tid & 15) * 4;
#pragma unroll
    for (int i = 0; i < 4; i++) {
        int c = i * 16 + (tid >> 4);
        ushort4 o;
        o.x = f2bf(tile[r4 + 0][c]);
        o.y = f2bf(tile[r4 + 1][c]);
        o.z = f2bf(tile[r4 + 2][c]);
        o.w = f2bf(tile[r4 + 3][c]);
        *(ushort4*)&outp[(size_t)(c0 + c) * R + r0 + r4] = o;
    }
}

// ---------------- gating / routing ----------------

__global__ __launch_bounds__(256) void gating_kernel(const float* __restrict__ x,
                                                     const float* __restrict__ wg,
                                                     int* __restrict__ topk_e,
                                                     float* __restrict__ topk_w,
                                                     int* __restrict__ counts) {
    int wave = threadIdx.x >> 6, lane = threadIdx.x & 63;
    int t = blockIdx.x * 4 + wave;
    const float* xr = x + (size_t)t * DIM;
    float acc[NEXP];
#pragma unroll
    for (int e = 0; e < NEXP; e++) acc[e] = 0.f;
    for (int it = 0; it < DIM / 64; it++) {
        int d = it * 64 + lane;
        float xv = xr[d];
        const float4* wr = (const float4*)(wg + d * NEXP);
        float4 w0 = wr[0], w1 = wr[1];
        acc[0] += xv * w0.x; acc[1] += xv * w0.y; acc[2] += xv * w0.z; acc[3] += xv * w0.w;
        acc[4] += xv * w1.x; acc[5] += xv * w1.y; acc[6] += xv * w1.z; acc[7] += xv * w1.w;
    }
#pragma unroll
    for (int e = 0; e < NEXP; e++) {
#pragma unroll
        for (int off = 32; off > 0; off >>= 1) acc[e] += __shfl_xor(acc[e], off);
    }
    if (lane == 0) {
        int e1 = 0; float l1 = acc[0];
        for (int e = 1; e < NEXP; e++) if (acc[e] > l1) { l1 = acc[e]; e1 = e; }
        int e2 = -1; float l2 = -3.4e38f;
        for (int e = 0; e < NEXP; e++) if (e != e1 && acc[e] > l2) { l2 = acc[e]; e2 = e; }
        float w1v = 1.f / (1.f + expf(l2 - l1));   // softmax top-2 renormalized
        topk_e[t * 2]     = e1;  topk_e[t * 2 + 1] = e2;
        topk_w[t * 2]     = w1v; topk_w[t * 2 + 1] = 1.f - w1v;
        atomicAdd(&counts[e1], 1);
        atomicAdd(&counts[e2], 1);
    }
}

__global__ void prefix_kernel(const int* __restrict__ counts, int* __restrict__ offs) {
    if (threadIdx.x == 0) {
        int s = 0;
        for (int e = 0; e < NEXP; e++) { offs[e] = s; s += counts[e]; }
        offs[NEXP] = s;
    }
}

__global__ __launch_bounds__(256) void scatter_kernel(const int* __restrict__ topk_e,
                                                      const float* __restrict__ topk_w,
                                                      const int* __restrict__ offs,
                                                      int* __restrict__ cursors,
                                                      int* __restrict__ entry_token,
                                                      int* __restrict__ entry_pos) {
    int t = blockIdx.x * 256 + threadIdx.x;   // grid exact
#pragma unroll
    for (int k = 0; k < TOPK; k++) {
        int e = topk_e[t * 2 + k];
        int pos = offs[e] + atomicAdd(&cursors[e], 1);
        entry_token[pos] = t;
        entry_pos[t * 2 + k] = pos;
    }
}

// ---------------- GEMM1: h = relu(x[tok] @ W1_e + b1_e) ----------------
// 256x256 tile, BK=64, 512 threads (8 waves, 2M x 4N), 4-phase K-loop with
// counted vmcnt(6) (never drained to 0 in the main loop), raw s_barrier
// (no compiler vmcnt(0) drain), setprio(1) around 16-MFMA clusters.
// LDS: per buffer 2 K-halves of A (256x32) and B (256x32), XOR slot swizzle
// (16B slot ^ ((row>>1)&3)) -> conflict-free ds_read_b128 fragment reads,
// applied via pre-swizzled global source (global_load_lds dest is linear).
//
// Half-tile issue slots (steady state, tile t computed in buf=t&1):
//   phase1: B-kh0(t+1)   phase2: A-kh1(t+1)   phase3: B-kh1(t+1)
//   phase4: A-kh0(t+2) -> buf[(t+2)&1] == current buf (its kh0 reads are done)
// vmcnt(6) at phase2 (covers A-kh1/B-kh1 of t, read in phases 3-4) and at
// phase4 (covers A-kh0/B-kh0 of t+1, read in phases 1-2 of t+1). Every read
// is covered by a per-wave wait in an earlier phase followed by s_barrier.
// Tail tiles issue clamped (dummy) prefetches so vmcnt counting stays uniform.

__global__ __launch_bounds__(512, 2) void gemm1_kernel(
    const unsigned short* __restrict__ xb,    // [N_TOK][DIM] bf16
    const unsigned short* __restrict__ w1t,   // [E][FFN][DIM] bf16
    const float* __restrict__ b1,             // [E][FFN]
    const int* __restrict__ offs,
    const int* __restrict__ entry_token,
    unsigned short* __restrict__ h)           // [NENT+256][FFN] bf16
{
    constexpr int T = DIM / 64;               // 16 K-tiles
    int bid  = blockIdx.x;
    int e    = bid & 7;
    int mt   = (bid >> 3) % MAXMT;
    int nt   = bid / (8 * MAXMT);             // 0..15
    int base = offs[e];
    int cnt  = offs[e + 1] - base;
    int m0   = mt * 256;
    if (m0 >= cnt) return;
    int f0   = nt * 256;

    __shared__ unsigned short As[2 * 2 * 8192];   // [buf][kh][256 rows][32 cols] = 64 KB
    __shared__ unsigned short Bs[2 * 2 * 8192];   // 64 KB
    __shared__ int toks[256];

    int tid = threadIdx.x;
    if (tid < 256) {
        int r = m0 + tid;
        toks[tid] = entry_token[base + (r < cnt ? r : 0)];
    }
    __syncthreads();

    int wid = tid >> 6, lane = tid & 63;
    int wm = (wid >> 2) * 128;                // 0 / 128
    int wn = (wid & 3) * 64;                  // 0..192

    // staging: per half-tile (region 256r x 32c) each thread does 2 x 16B loads:
    // rows r0 = wid*16 + (lane>>2) and r1 = 128 + r0; LDS dest linear, global
    // source column slot pre-swizzled: slot = (lane&3) ^ ((lane>>3)&3).
    int l4 = lane >> 2;
    int srcoff = ((lane & 3) ^ ((lane >> 3) & 3)) * 8;   // shorts
    int r0 = wid * 16 + l4, r1 = 128 + r0;
    const unsigned short* aS0 = xb + (size_t)toks[r0] * DIM + srcoff;
    const unsigned short* aS1 = xb + (size_t)toks[r1] * DIM + srcoff;
    const unsigned short* bS0 = w1t + ((size_t)e * FFN + f0 + r0) * DIM + srcoff;
    const unsigned short* bS1 = w1t + ((size_t)e * FFN + f0 + r1) * DIM + srcoff;

#define STAGE_A1(buf, kh, ko) do { \
    GLOAD_LDS16(aS0 + (ko) + (kh) * 32, &As[(buf) * 16384 + (kh) * 8192 + wid * 512]); \
    GLOAD_LDS16(aS1 + (ko) + (kh) * 32, &As[(buf) * 16384 + (kh) * 8192 + 4096 + wid * 512]); \
} while (0)
#define STAGE_B1(buf, kh, ko) do { \
    GLOAD_LDS16(bS0 + (ko) + (kh) * 32, &Bs[(buf) * 16384 + (kh) * 8192 + wid * 512]); \
    GLOAD_LDS16(bS1 + (ko) + (kh) * 32, &Bs[(buf) * 16384 + (kh) * 8192 + 4096 + wid * 512]); \
} while (0)

    floatx4 acc[8][4];
#pragma unroll
    for (int i = 0; i < 8; i++)
#pragma unroll
        for (int j = 0; j < 4; j++) acc[i][j] = (floatx4)0.f;

    int rm = lane & 15, quad = lane >> 4;
    int slf  = (quad ^ ((rm >> 1) & 3)) * 8;         // swizzled 16B frag slot
    int aoff = (wm + rm) * 32 + slf;
    int boff = (wn + rm) * 32 + slf;

    // prologue: fill pipeline 5 half-tiles deep, then wait for the oldest 2.
    STAGE_A1(0, 0, 0);
    STAGE_B1(0, 0, 0);
    STAGE_A1(0, 1, 0);
    STAGE_B1(0, 1, 0);
    STAGE_A1(1, 0, 64);
    WAITV6();
    BARRIER();

    short8 alo[4], ahi[4], bfr[4];
    for (int t = 0; t < T; ++t) {
        int buf = t & 1, nxt = buf ^ 1;
        int kN1 = ((t + 1 < T) ? (t + 1) : (T - 1)) * 64;
        int kN2 = ((t + 2 < T) ? (t + 2) : (T - 1)) * 64;
        const unsigned short* Ab = &As[buf * 16384];
        const unsigned short* Bb = &Bs[buf * 16384];

        // ---- phase 1: ksub0, mi 0-3, all ni (reads: 8 A + 4 B) ----
#pragma unroll
        for (int i = 0; i < 4; ++i) alo[i] = *(const short8*)&Ab[aoff + i * 512];
#pragma unroll
        for (int i = 0; i < 4; ++i) bfr[i] = *(const short8*)&Bb[boff + i * 512];
        STAGE_B1(nxt, 0, kN1);
        BARRIER(); SCHED0();
        __builtin_amdgcn_s_setprio(1);
#pragma unroll
        for (int i = 0; i < 4; ++i)
#pragma unroll
            for (int j = 0; j < 4; ++j)
                acc[i][j] = __builtin_amdgcn_mfma_f32_16x16x32_bf16(alo[i], bfr[j], acc[i][j], 0, 0, 0);
        __builtin_amdgcn_s_setprio(0);
        SCHED0(); BARRIER();

        // ---- phase 2: ksub0, mi 4-7 ----
#pragma unroll
        for (int i = 0; i < 4; ++i) ahi[i] = *(const short8*)&Ab[aoff + (i + 4) * 512];
        STAGE_A1(nxt, 1, kN1);
        WAITV6();
        BARRIER(); SCHED0();
        __builtin_amdgcn_s_setprio(1);
#pragma unroll
        for (int i = 0; i < 4; ++i)
#pragma unroll
            for (int j = 0; j < 4; ++j)
                acc[i + 4][j] = __builtin_amdgcn_mfma_f32_16x16x32_bf16(ahi[i], bfr[j], acc[i + 4][j], 0, 0, 0);
        __builtin_amdgcn_s_setprio(0);
        SCHED0(); BARRIER();

        // ---- phase 3: ksub1, mi 0-3, all ni ----
#pragma unroll
        for (int i = 0; i < 4; ++i) alo[i] = *(const short8*)&Ab[8192 + aoff + i * 512];
#pragma unroll
        for (int i = 0; i < 4; ++i) bfr[i] = *(const short8*)&Bb[8192 + boff + i * 512];
        STAGE_B1(nxt, 1, kN1);
        BARRIER(); SCHED0();
        __builtin_amdgcn_s_setprio(1);
#pragma unroll
        for (int i = 0; i < 4; ++i)
#pragma unroll
            for (int j = 0; j < 4; ++j)
                acc[i][j] = __builtin_amdgcn_mfma_f32_16x16x32_bf16(alo[i], bfr[j], acc[i][j], 0, 0, 0);
        __builtin_amdgcn_s_setprio(0);
        SCHED0(); BARRIER();

        // ---- phase 4: ksub1, mi 4-7 ----
#pragma unroll
        for (int i = 0; i < 4; ++i) ahi[i] = *(const short8*)&Ab[8192 + aoff + (i + 4) * 512];
        STAGE_A1(buf, 0, kN2);   // A-kh0(t+2) -> buf[(t+2)&1] == buf; its kh0 reads finished in phase 2
        WAITV6();
        BARRIER(); SCHED0();
        __builtin_amdgcn_s_setprio(1);
#pragma unroll
        for (int i = 0; i < 4; ++i)
#pragma unroll
            for (int j = 0; j < 4; ++j)
                acc[i + 4][j] = __builtin_amdgcn_mfma_f32_16x16x32_bf16(ahi[i], bfr[j], acc[i + 4][j], 0, 0, 0);
        __builtin_amdgcn_s_setprio(0);
        SCHED0(); BARRIER();
    }
    WAITV0();   // drain dummy tail prefetches before LDS goes out of scope

#undef STAGE_A1
#undef STAGE_B1

    // epilogue: D layout col = lane&15, row = quad*4 + r
    float bs[4];
#pragma unroll
    for (int j = 0; j < 4; ++j) bs[j] = b1[(size_t)e * FFN + f0 + wn + j * 16 + rm];
#pragma unroll
    for (int i = 0; i < 8; ++i) {
        int rb = wm + i * 16 + quad * 4;
#pragma unroll
        for (int j = 0; j < 4; ++j) {
            int f = f0 + wn + j * 16 + rm;
            floatx4 v = acc[i][j];
#pragma unroll
            for (int r = 0; r < 4; ++r) {
                int row = m0 + rb + r;
                if (row < cnt) {
                    float tv = v[r] + bs[j];
                    tv = tv > 0.f ? tv : 0.f;
                    h[(size_t)(base + row) * FFN + f] = f2bf(tv);
                }
            }
        }
    }
}

// ---------------- GEMM2: o[entry] = h @ W2_e + b2_e ----------------
// 256x128 tile (smaller N-tile: N=1024 at 256x256 gives only ~272 jobs ->
// 2 serial block-generations on 256 CUs; 256x128 gives ~544 jobs), BK=64,
// 512 threads (8 waves, 4M x 2N), 2-phase K-loop (ksub0 / ksub1), same
// counted-vmcnt(6) discipline: each phase issues one K-half group
// (A: 2 loads, B: 1 load) one tile ahead; K=4096 -> 64 tiles.

__global__ __launch_bounds__(512, 2) void gemm2_kernel(
    const unsigned short* __restrict__ h,     // [NENT+256][FFN]
    const unsigned short* __restrict__ w2t,   // [E][DIM][FFN]
    const float* __restrict__ b2,             // [E][DIM]
    const int* __restrict__ offs,
    unsigned short* __restrict__ o)           // [NENT][DIM] bf16
{
    constexpr int T = FFN / 64;               // 64 K-tiles
    int bid  = blockIdx.x;
    int e    = bid & 7;
    int mt   = (bid >> 3) % MAXMT;
    int nt   = bid / (8 * MAXMT);             // 0..7
    int base = offs[e];
    int cnt  = offs[e + 1] - base;
    int m0   = mt * 256;
    if (m0 >= cnt) return;
    int n0   = nt * 128;

    __shared__ unsigned short As[2 * 2 * 8192];   // [buf][kh][256r][32c] = 64 KB
    __shared__ unsigned short Bs[2 * 2 * 4096];   // [buf][kh][128r][32c] = 32 KB

    int tid = threadIdx.x;
    int wid = tid >> 6, lane = tid & 63;
    int wm = (wid >> 1) * 64;                 // 0..192
    int wn = (wid & 1) * 64;                  // 0 / 64

    int l4 = lane >> 2;
    int srcoff = ((lane & 3) ^ ((lane >> 3) & 3)) * 8;
    int r0 = wid * 16 + l4, r1 = 128 + r0;
    const unsigned short* aS0 = h + (size_t)(base + m0 + r0) * FFN + srcoff;
    const unsigned short* aS1 = h + (size_t)(base + m0 + r1) * FFN + srcoff;
    const unsigned short* bS  = w2t + ((size_t)e * DIM + n0 + r0) * FFN + srcoff;

#define STAGE_A2(buf, kh, ko) do { \
    GLOAD_LDS16(aS0 + (ko) + (kh) * 32, &As[(buf) * 16384 + (kh) * 8192 + wid * 512]); \
    GLOAD_LDS16(aS1 + (ko) + (kh) * 32, &As[(buf) * 16384 + (kh) * 8192 + 4096 + wid * 512]); \
} while (0)
#define STAGE_B2(buf, kh, ko) do { \
    GLOAD_LDS16(bS + (ko) + (kh) * 32, &Bs[(buf) * 8192 + (kh) * 4096 + wid * 512]); \
} while (0)

    floatx4 acc[4][4];
#pragma unroll
    for (int i = 0; i < 4; i++)
#pragma unroll
        for (int j = 0; j < 4; j++) acc[i][j] = (floatx4)0.f;

    int rm = lane & 15, quad = lane >> 4;
    int slf  = (quad ^ ((rm >> 1) & 3)) * 8;
    int aoff = (wm + rm) * 32 + slf;
    int boff = (wn + rm) * 32 + slf;

    // prologue: 3 K-half groups deep (9 loads), wait for oldest group (3).
    STAGE_A2(0, 0, 0);  STAGE_B2(0, 0, 0);    // A0B0(0)
    STAGE_A2(0, 1, 0);  STAGE_B2(0, 1, 0);    // A1B1(0)
    STAGE_A2(1, 0, 64); STAGE_B2(1, 0, 64);   // A0B0(1)
    WAITV6();
    BARRIER();

    short8 af[4], bfr[4];
    for (int t = 0; t < T; ++t) {
        int buf = t & 1, nxt = buf ^ 1;
        int kN1 = ((t + 1 < T) ? (t + 1) : (T - 1)) * 64;
        int kN2 = ((t + 2 < T) ? (t + 2) : (T - 1)) * 64;
        const unsigned short* Ab = &As[buf * 16384];
        const unsigned short* Bb = &Bs[buf * 8192];

        // ---- phase 1: ksub0 ----
#pragma unroll
        for (int i = 0; i < 4; ++i) af[i]  = *(const short8*)&Ab[aoff + i * 512];
#pragma unroll
        for (int i = 0; i < 4; ++i) bfr[i] = *(const short8*)&Bb[boff + i * 512];
        STAGE_A2(nxt, 1, kN1); STAGE_B2(nxt, 1, kN1);   // A1B1(t+1)
        WAITV6();
        BARRIER(); SCHED0();
        __builtin_amdgcn_s_setprio(1);
#pragma unroll
        for (int i = 0; i < 4; ++i)
#pragma unroll
            for (int j = 0; j < 4; ++j)
                acc[i][j] = __builtin_amdgcn_mfma_f32_16x16x32_bf16(af[i], bfr[j], acc[i][j], 0, 0, 0);
        __builtin_amdgcn_s_setprio(0);
        SCHED0(); BARRIER();

        // ---- phase 2: ksub1 ----
#pragma unroll
        for (int i = 0; i < 4; ++i) af[i]  = *(const short8*)&Ab[8192 + aoff + i * 512];
#pragma unroll
        for (int i = 0; i < 4; ++i) bfr[i] = *(const short8*)&Bb[4096 + boff + i * 512];
        STAGE_A2(buf, 0, kN2); STAGE_B2(buf, 0, kN2);   // A0B0(t+2) -> current buf, kh0 reads done
        WAITV6();
        BARRIER(); SCHED0();
        __builtin_amdgcn_s_setprio(1);
#pragma unroll
        for (int i = 0; i < 4; ++i)
#pragma unroll
            for (int j = 0; j < 4; ++j)
                acc[i][j] = __builtin_amdgcn_mfma_f32_16x16x32_bf16(af[i], bfr[j], acc[i][j], 0, 0, 0);
        __builtin_amdgcn_s_setprio(0);
        SCHED0(); BARRIER();
    }
    WAITV0();

#undef STAGE_A2
#undef STAGE_B2

    float bs[4];
#pragma unroll
    for (int j = 0; j < 4; ++j) bs[j] = b2[(size_t)e * DIM + n0 + wn + j * 16 + rm];
#pragma unroll
    for (int i = 0; i < 4; ++i) {
        int rb = wm + i * 16 + quad * 4;
#pragma unroll
        for (int j = 0; j < 4; ++j) {
            int n = n0 + wn + j * 16 + rm;
            floatx4 v = acc[i][j];
#pragma unroll
            for (int r = 0; r < 4; ++r) {
                int row = m0 + rb + r;
                if (row < cnt)
                    o[(size_t)(base + row) * DIM + n] = f2bf(v[r] + bs[j]);
            }
        }
    }
}

// ---------------- combine: y[t] = w0*o[p0] + w1*o[p1] ----------------

__global__ __launch_bounds__(256) void combine_kernel(const unsigned short* __restrict__ o,
                                                      const int* __restrict__ entry_pos,
                                                      const float* __restrict__ topk_w,
                                                      float* __restrict__ y) {
    int t = blockIdx.x;
    int d = threadIdx.x * 4;
    int p0 = entry_pos[t * 2], p1 = entry_pos[t * 2 + 1];
    float w0 = topk_w[t * 2], w1 = topk_w[t * 2 + 1];
    ushort4 a = *(const ushort4*)&o[(size_t)p0 * DIM + d];
    ushort4 b = *(const ushort4*)&o[(size_t)p1 * DIM + d];
    float4 r;
    r.x = w0 * bf2f(a.x) + w1 * bf2f(b.x);
    r.y = w0 * bf2f(a.y) + w1 * bf2f(b.y);
    r.z = w0 * bf2f(a.z) + w1 * bf2f(b.z);
    r.w = w0 * bf2f(a.w) + w1 * bf2f(b.w);
    *(float4*)&y[(size_t)t * DIM + d] = r;
}

// ---------------- launch ----------------

extern "C" void kernel_launch(void* const* d_in, const int* in_sizes, int n_in,
                              void* d_out, int out_size, void* d_ws, size_t ws_size,
                              hipStream_t stream) {
    const float* x  = (const float*)d_in[0];
    const float* Wg = (const float*)d_in[1];
    const float* W1 = (const float*)d_in[2];
    const float* b1 = (const float*)d_in[3];
    const float* W2 = (const float*)d_in[4];
    const float* b2 = (const float*)d_in[5];
    float* y = (float*)d_out;

    char* p = (char*)d_ws;
    unsigned short* xb  = (unsigned short*)p; p += (size_t)N_TOK * DIM * 2;            // 16 MB
    unsigned short* w1t = (unsigned short*)p; p += (size_t)NEXP * DIM * FFN * 2;       // 64 MB
    unsigned short* w2t = (unsigned short*)p; p += (size_t)NEXP * DIM * FFN * 2;       // 64 MB
    unsigned short* h   = (unsigned short*)p; p += (size_t)(NENT + 256) * FFN * 2;     // 136 MB
    int*   topk_e      = (int*)p;   p += (size_t)N_TOK * TOPK * 4;
    float* topk_w      = (float*)p; p += (size_t)N_TOK * TOPK * 4;
    int*   entry_token = (int*)p;   p += (size_t)NENT * 4;
    int*   entry_pos   = (int*)p;   p += (size_t)NENT * 4;
    int*   counts      = (int*)p;   p += NEXP * 4;
    int*   cursors     = (int*)p;   p += NEXP * 4;
    int*   offs        = (int*)p;   p += (NEXP + 1) * 4;

    // o overlays w1t: w1t is consumed by gemm1, o is produced by gemm2 (later
    // in stream order). NENT*DIM*2 = 33.6 MB <= 64 MB.
    unsigned short* o = w1t;

    hipMemsetAsync(counts, 0, NEXP * 4 * 2, stream);   // counts + cursors (adjacent)
    // zero h's 256-row pad so gemm2's over-read rows (outputs discarded) are finite
    hipMemsetAsync(h + (size_t)NENT * FFN, 0, (size_t)256 * FFN * 2, stream);

    cvt_x_kernel<<<(N_TOK * DIM) / (256 * 4), 256, 0, stream>>>((const float4*)x, (ushort4*)xb);
    transpose_cvt<<<dim3(FFN / 64, DIM / 64, NEXP), 256, 0, stream>>>(W1, w1t, DIM, FFN);
    transpose_cvt<<<dim3(DIM / 64, FFN / 64, NEXP), 256, 0, stream>>>(W2, w2t, FFN, DIM);
    gating_kernel<<<N_TOK / 4, 256, 0, stream>>>(x, Wg, topk_e, topk_w, counts);
    prefix_kernel<<<1, 64, 0, stream>>>(counts, offs);
    scatter_kernel<<<N_TOK / 256, 256, 0, stream>>>(topk_e, topk_w, offs, cursors, entry_token, entry_pos);
    gemm1_kernel<<<NEXP * MAXMT * (FFN / 256), 512, 0, stream>>>(xb, w1t, b1, offs, entry_token, h);
    gemm2_kernel<<<NEXP * MAXMT * (DIM / 128), 512, 0, stream>>>(h, w2t, b2, offs, o);
    combine_kernel<<<N_TOK, 256, 0, stream>>>(o, entry_pos, topk_w, y);
}

// Round 3
// 1048.009 us; speedup vs baseline: 1.0615x; 1.0615x over previous
//
#include <hip/hip_runtime.h>

#define N_TOK 8192
#define DIM   1024
#define FFN   4096
#define NEXP  8
#define TOPK  2
#define NENT  (N_TOK * TOPK)   // 16384
#define MAXM  20               // max 128-row m-tiles per expert (cnt<=2560; mean 2048, sigma 42)

using short8  = __attribute__((ext_vector_type(8))) short;
using floatx4 = __attribute__((ext_vector_type(4))) float;

__device__ __forceinline__ unsigned short f2bf(float f) {
    union { float f; unsigned u; } v; v.f = f;
    unsigned r = v.u + 0x7fffu + ((v.u >> 16) & 1u);   // round-to-nearest-even
    return (unsigned short)(r >> 16);
}

__device__ __forceinline__ float bf2f(unsigned short s) {
    union { unsigned u; float f; } v; v.u = ((unsigned)s) << 16;
    return v.f;
}

#define GLOAD_LDS16(gptr, lptr) __builtin_amdgcn_global_load_lds( \
    (__attribute__((address_space(1))) void*)(void*)(gptr),       \
    (__attribute__((address_space(3))) void*)(lptr), 16, 0, 0)

// ---------------- conversion kernels ----------------

// in: [E][R][C] f32 -> out: [E][C][R] bf16; 64x64 tiles, ushort4 writes
__global__ __launch_bounds__(256) void transpose_cvt(const float* __restrict__ in,
                                                     unsigned short* __restrict__ out,
                                                     int R, int C) {
    __shared__ float tile[64][65];
    int e  = blockIdx.z;
    int c0 = blockIdx.x * 64;
    int r0 = blockIdx.y * 64;
    const float* inp = in + (size_t)e * R * C;
    unsigned short* outp = out + (size_t)e * R * C;
    int tid = threadIdx.x;
    int lrow = tid >> 6, lcol = tid & 63;
#pragma unroll
    for (int i = 0; i < 16; i++) {
        int r = i * 4 + lrow;
        tile[r][lcol] = inp[(size_t)(r0 + r) * C + c0 + lcol];
    }
    __syncthreads();
    int r4 = (tid & 15) * 4;
#pragma unroll
    for (int i = 0; i < 4; i++) {
        int c = i * 16 + (tid >> 4);
        ushort4 o;
        o.x = f2bf(tile[r4 + 0][c]);
        o.y = f2bf(tile[r4 + 1][c]);
        o.z = f2bf(tile[r4 + 2][c]);
        o.w = f2bf(tile[r4 + 3][c]);
        *(ushort4*)&outp[(size_t)(c0 + c) * R + r0 + r4] = o;
    }
}

// ---------------- gating / routing (x->bf16 conversion fused in) ----------------

__global__ __launch_bounds__(256) void gating_kernel(const float* __restrict__ x,
                                                     const float* __restrict__ wg,
                                                     unsigned short* __restrict__ xb,
                                                     int* __restrict__ topk_e,
                                                     float* __restrict__ topk_w,
                                                     int* __restrict__ counts) {
    int wave = threadIdx.x >> 6, lane = threadIdx.x & 63;
    int t = blockIdx.x * 4 + wave;
    const float* xr = x + (size_t)t * DIM;
    unsigned short* xbr = xb + (size_t)t * DIM;
    float acc[NEXP];
#pragma unroll
    for (int e = 0; e < NEXP; e++) acc[e] = 0.f;
    for (int it = 0; it < DIM / 64; it++) {
        int d = it * 64 + lane;
        float xv = xr[d];
        xbr[d] = f2bf(xv);                       // fused bf16 conversion of x
        const float4* wr = (const float4*)(wg + d * NEXP);
        float4 w0 = wr[0], w1 = wr[1];
        acc[0] += xv * w0.x; acc[1] += xv * w0.y; acc[2] += xv * w0.z; acc[3] += xv * w0.w;
        acc[4] += xv * w1.x; acc[5] += xv * w1.y; acc[6] += xv * w1.z; acc[7] += xv * w1.w;
    }
#pragma unroll
    for (int e = 0; e < NEXP; e++) {
#pragma unroll
        for (int off = 32; off > 0; off >>= 1) acc[e] += __shfl_xor(acc[e], off);
    }
    if (lane == 0) {
        int e1 = 0; float l1 = acc[0];
        for (int e = 1; e < NEXP; e++) if (acc[e] > l1) { l1 = acc[e]; e1 = e; }
        int e2 = -1; float l2 = -3.4e38f;
        for (int e = 0; e < NEXP; e++) if (e != e1 && acc[e] > l2) { l2 = acc[e]; e2 = e; }
        float w1v = 1.f / (1.f + expf(l2 - l1));   // softmax top-2 renormalized
        topk_e[t * 2]     = e1;  topk_e[t * 2 + 1] = e2;
        topk_w[t * 2]     = w1v; topk_w[t * 2 + 1] = 1.f - w1v;
        atomicAdd(&counts[e1], 1);
        atomicAdd(&counts[e2], 1);
    }
}

// scatter with the tiny 8-element prefix computed per-thread (prefix_kernel fused)
__global__ __launch_bounds__(256) void scatter_kernel(const int* __restrict__ topk_e,
                                                      const float* __restrict__ topk_w,
                                                      const int* __restrict__ counts,
                                                      int* __restrict__ offs,
                                                      int* __restrict__ cursors,
                                                      int* __restrict__ entry_token,
                                                      int* __restrict__ entry_pos) {
    int off_[NEXP]; int s = 0;
#pragma unroll
    for (int e = 0; e < NEXP; e++) { off_[e] = s; s += counts[e]; }
    if (blockIdx.x == 0 && threadIdx.x == 0) {
#pragma unroll
        for (int e = 0; e < NEXP; e++) offs[e] = off_[e];
        offs[NEXP] = s;
    }
    int t = blockIdx.x * 256 + threadIdx.x;   // grid exact
#pragma unroll
    for (int k = 0; k < TOPK; k++) {
        int e = topk_e[t * 2 + k];
        int pos = off_[e] + atomicAdd(&cursors[e], 1);
        entry_token[pos] = t;
        entry_pos[t * 2 + k] = pos;
    }
}

// ---------------- GEMM1: h = relu(x[tok] @ W1_e + b1_e) ----------------
// 128x128 tile, BK=32, XOR swizzle (2-way = free), double-buffered LDS,
// 3 blocks/CU. XCD-aware bijective block swizzle: groups g=(e,nt) are
// distributed g%8 -> XCD (dispatch round-robins blockIdx%8 across XCDs);
// within an XCD, all m-tiles of one group run consecutively so the B panel
// (w1t[e][f0:f0+128][:], 0.5 MB) stays L2-resident, and the 4 consecutive
// groups sharing an expert re-visit that expert's gathered A rows while warm.

__global__ __launch_bounds__(256, 3) void gemm1_kernel(
    const unsigned short* __restrict__ xb,    // [N_TOK][DIM] bf16
    const unsigned short* __restrict__ w1t,   // [E][FFN][DIM] bf16
    const float* __restrict__ b1,             // [E][FFN]
    const int* __restrict__ offs,
    const int* __restrict__ entry_token,
    unsigned short* __restrict__ h)           // [NENT+128][FFN] bf16
{
    int bid   = blockIdx.x;
    int xcd   = bid & 7;
    int inner = bid >> 3;                 // 0 .. 32*MAXM-1
    int gq    = inner / MAXM;             // 0..31
    int mt    = inner - gq * MAXM;        // 0..MAXM-1
    int g     = gq * 8 + xcd;             // group id 0..255
    int e     = g >> 5;                   // 0..7
    int nt    = g & 31;                   // 0..31
    int base = offs[e];
    int cnt  = offs[e + 1] - base;
    int m0   = mt * 128;
    if (m0 >= cnt) return;
    int f0   = nt * 128;

    __shared__ unsigned short As[2][128 * 32];   // 2 x 8 KB
    __shared__ unsigned short Bs[2][128 * 32];
    __shared__ int toks[128];

    int tid = threadIdx.x;
    if (tid < 128) {
        int r = m0 + tid;
        toks[tid] = entry_token[base + (r < cnt ? r : 0)];
    }
    __syncthreads();

    int wave = tid >> 6, lane = tid & 63;
    int wm = (wave >> 1) * 64, wn = (wave & 1) * 64;

    // staging: wave stages rows [wave*32, +32), 2 chunks of 16 rows each
    int lr = lane >> 2, sl = lane & 3;
    int g0 = (sl ^ ((lr >> 1) & 3)) * 8;   // swizzled global slot (shorts)
    const unsigned short* aG[2];
    const unsigned short* bG[2];
    int ldsOff[2];
#pragma unroll
    for (int c = 0; c < 2; c++) {
        int row = wave * 32 + c * 16 + lr;
        aG[c] = xb + (size_t)toks[row] * DIM + g0;
        bG[c] = w1t + ((size_t)e * FFN + f0 + row) * DIM + g0;
        ldsOff[c] = (wave * 32 + c * 16) * 32;
    }

    floatx4 acc[4][4];
#pragma unroll
    for (int i = 0; i < 4; i++)
#pragma unroll
        for (int j = 0; j < 4; j++) acc[i][j] = (floatx4)0.f;

    int quad = lane >> 4, rm = lane & 15;
    int slf  = (quad ^ ((rm >> 1) & 3)) * 8;   // fragment slot (shorts)
    int arow = (wm + rm) * 32;
    int brow = (wn + rm) * 32;

    // prologue: stage tile 0 into buffer 0
#pragma unroll
    for (int c = 0; c < 2; c++) {
        GLOAD_LDS16(aG[c], &As[0][ldsOff[c]]);
        GLOAD_LDS16(bG[c], &Bs[0][ldsOff[c]]);
        aG[c] += 32; bG[c] += 32;
    }

    int cur = 0;
    for (int kk = 0; kk < DIM / 32; kk++) {
        __syncthreads();   // drains prefetch issued last iter; publishes buf[cur]
        short8 af[4], bfr[4];
#pragma unroll
        for (int mi = 0; mi < 4; mi++) af[mi] = *(const short8*)&As[cur][arow + mi * 512 + slf];
#pragma unroll
        for (int ni = 0; ni < 4; ni++) bfr[ni] = *(const short8*)&Bs[cur][brow + ni * 512 + slf];
        if (kk + 1 < DIM / 32) {
            int nxt = cur ^ 1;
#pragma unroll
            for (int c = 0; c < 2; c++) {
                GLOAD_LDS16(aG[c], &As[nxt][ldsOff[c]]);
                GLOAD_LDS16(bG[c], &Bs[nxt][ldsOff[c]]);
                aG[c] += 32; bG[c] += 32;
            }
        }
#pragma unroll
        for (int mi = 0; mi < 4; mi++)
#pragma unroll
            for (int ni = 0; ni < 4; ni++)
                acc[mi][ni] = __builtin_amdgcn_mfma_f32_16x16x32_bf16(af[mi], bfr[ni], acc[mi][ni], 0, 0, 0);
        cur ^= 1;
    }

    // epilogue: D layout col = lane&15, row = quad*4 + r
#pragma unroll
    for (int mi = 0; mi < 4; mi++) {
        int mbase = wm + mi * 16 + quad * 4;
#pragma unroll
        for (int ni = 0; ni < 4; ni++) {
            int f = f0 + wn + ni * 16 + rm;
            float bias = b1[e * FFN + f];
            floatx4 v = acc[mi][ni];
#pragma unroll
            for (int r = 0; r < 4; r++) {
                int row = m0 + mbase + r;
                if (row < cnt) {
                    float t = v[r] + bias;
                    t = t > 0.f ? t : 0.f;
                    h[(size_t)(base + row) * FFN + f] = f2bf(t);
                }
            }
        }
    }
}

// ---------------- GEMM2: o[entry] = h @ W2_e + b2_e (bf16 stores) ----------------
// Same 128x128 structure; XCD swizzle groups g=(e,nt): XCD x serves one nt
// across all experts, so the w2t panel (1 MB region spread across mt steps)
// stays L2-resident while its ~16-20 m-tiles run.

__global__ __launch_bounds__(256, 3) void gemm2_kernel(
    const unsigned short* __restrict__ h,     // [NENT+128][FFN]
    const unsigned short* __restrict__ w2t,   // [E][DIM][FFN]
    const float* __restrict__ b2,             // [E][DIM]
    const int* __restrict__ offs,
    unsigned short* __restrict__ o)           // [NENT+128][DIM] bf16
{
    int bid   = blockIdx.x;
    int xcd   = bid & 7;
    int inner = bid >> 3;                 // 0 .. 8*MAXM-1
    int gq    = inner / MAXM;             // 0..7
    int mt    = inner - gq * MAXM;        // 0..MAXM-1
    int g     = gq * 8 + xcd;             // group id 0..63
    int e     = g >> 3;                   // 0..7
    int nt    = g & 7;                    // 0..7
    int base = offs[e];
    int cnt  = offs[e + 1] - base;
    int m0   = mt * 128;
    if (m0 >= cnt) return;
    int n0   = nt * 128;

    __shared__ unsigned short As[2][128 * 32];
    __shared__ unsigned short Bs[2][128 * 32];

    int tid = threadIdx.x;
    int wave = tid >> 6, lane = tid & 63;
    int wm = (wave >> 1) * 64, wn = (wave & 1) * 64;

    int lr = lane >> 2, sl = lane & 3;
    int g0 = (sl ^ ((lr >> 1) & 3)) * 8;
    const unsigned short* aG[2];
    const unsigned short* bG[2];
    int ldsOff[2];
#pragma unroll
    for (int c = 0; c < 2; c++) {
        int row = wave * 32 + c * 16 + lr;
        aG[c] = h + (size_t)(base + m0 + row) * FFN + g0;
        bG[c] = w2t + ((size_t)e * DIM + n0 + row) * FFN + g0;
        ldsOff[c] = (wave * 32 + c * 16) * 32;
    }

    floatx4 acc[4][4];
#pragma unroll
    for (int i = 0; i < 4; i++)
#pragma unroll
        for (int j = 0; j < 4; j++) acc[i][j] = (floatx4)0.f;

    int quad = lane >> 4, rm = lane & 15;
    int slf  = (quad ^ ((rm >> 1) & 3)) * 8;
    int arow = (wm + rm) * 32;
    int brow = (wn + rm) * 32;

#pragma unroll
    for (int c = 0; c < 2; c++) {
        GLOAD_LDS16(aG[c], &As[0][ldsOff[c]]);
        GLOAD_LDS16(bG[c], &Bs[0][ldsOff[c]]);
        aG[c] += 32; bG[c] += 32;
    }

    int cur = 0;
    for (int kk = 0; kk < FFN / 32; kk++) {
        __syncthreads();
        short8 af[4], bfr[4];
#pragma unroll
        for (int mi = 0; mi < 4; mi++) af[mi] = *(const short8*)&As[cur][arow + mi * 512 + slf];
#pragma unroll
        for (int ni = 0; ni < 4; ni++) bfr[ni] = *(const short8*)&Bs[cur][brow + ni * 512 + slf];
        if (kk + 1 < FFN / 32) {
            int nxt = cur ^ 1;
#pragma unroll
            for (int c = 0; c < 2; c++) {
                GLOAD_LDS16(aG[c], &As[nxt][ldsOff[c]]);
                GLOAD_LDS16(bG[c], &Bs[nxt][ldsOff[c]]);
                aG[c] += 32; bG[c] += 32;
            }
        }
#pragma unroll
        for (int mi = 0; mi < 4; mi++)
#pragma unroll
            for (int ni = 0; ni < 4; ni++)
                acc[mi][ni] = __builtin_amdgcn_mfma_f32_16x16x32_bf16(af[mi], bfr[ni], acc[mi][ni], 0, 0, 0);
        cur ^= 1;
    }

#pragma unroll
    for (int mi = 0; mi < 4; mi++) {
        int mbase = wm + mi * 16 + quad * 4;
#pragma unroll
        for (int ni = 0; ni < 4; ni++) {
            int n = n0 + wn + ni * 16 + rm;
            float bias = b2[e * DIM + n];
            floatx4 v = acc[mi][ni];
#pragma unroll
            for (int r = 0; r < 4; r++) {
                int row = m0 + mbase + r;
                if (row < cnt)
                    o[(size_t)(base + row) * DIM + n] = f2bf(v[r] + bias);
            }
        }
    }
}

// ---------------- combine: y[t] = w0*o[p0] + w1*o[p1] ----------------

__global__ __launch_bounds__(256) void combine_kernel(const unsigned short* __restrict__ o,
                                                      const int* __restrict__ entry_pos,
                                                      const float* __restrict__ topk_w,
                                                      float* __restrict__ y) {
    int t = blockIdx.x;
    int d = threadIdx.x * 4;
    int p0 = entry_pos[t * 2], p1 = entry_pos[t * 2 + 1];
    float w0 = topk_w[t * 2], w1 = topk_w[t * 2 + 1];
    ushort4 a = *(const ushort4*)&o[(size_t)p0 * DIM + d];
    ushort4 b = *(const ushort4*)&o[(size_t)p1 * DIM + d];
    float4 r;
    r.x = w0 * bf2f(a.x) + w1 * bf2f(b.x);
    r.y = w0 * bf2f(a.y) + w1 * bf2f(b.y);
    r.z = w0 * bf2f(a.z) + w1 * bf2f(b.z);
    r.w = w0 * bf2f(a.w) + w1 * bf2f(b.w);
    *(float4*)&y[(size_t)t * DIM + d] = r;
}

// ---------------- launch ----------------

extern "C" void kernel_launch(void* const* d_in, const int* in_sizes, int n_in,
                              void* d_out, int out_size, void* d_ws, size_t ws_size,
                              hipStream_t stream) {
    const float* x  = (const float*)d_in[0];
    const float* Wg = (const float*)d_in[1];
    const float* W1 = (const float*)d_in[2];
    const float* b1 = (const float*)d_in[3];
    const float* W2 = (const float*)d_in[4];
    const float* b2 = (const float*)d_in[5];
    float* y = (float*)d_out;

    char* p = (char*)d_ws;
    unsigned short* xb  = (unsigned short*)p; p += (size_t)N_TOK * DIM * 2;          // 16 MB
    unsigned short* w1t = (unsigned short*)p; p += (size_t)NEXP * DIM * FFN * 2;     // 64 MB
    unsigned short* w2t = (unsigned short*)p; p += (size_t)NEXP * DIM * FFN * 2;     // 64 MB
    unsigned short* h   = (unsigned short*)p; p += (size_t)(NENT + 128) * FFN * 2;   // 129 MB
    int*   topk_e      = (int*)p;   p += (size_t)N_TOK * TOPK * 4;
    float* topk_w      = (float*)p; p += (size_t)N_TOK * TOPK * 4;
    int*   entry_token = (int*)p;   p += (size_t)NENT * 4;
    int*   entry_pos   = (int*)p;   p += (size_t)NENT * 4;
    int*   counts      = (int*)p;   p += NEXP * 4;
    int*   cursors     = (int*)p;   p += NEXP * 4;
    int*   offs        = (int*)p;   p += (NEXP + 1) * 4;

    // o overlays w1t: w1t is consumed by gemm1, o is produced by gemm2 (later
    // in stream order). (NENT+128)*DIM*2 = 33.8 MB <= 64 MB.
    unsigned short* o = w1t;

    hipMemsetAsync(counts, 0, NEXP * 4 * 2, stream);   // counts + cursors (adjacent)

    transpose_cvt<<<dim3(FFN / 64, DIM / 64, NEXP), 256, 0, stream>>>(W1, w1t, DIM, FFN);
    transpose_cvt<<<dim3(DIM / 64, FFN / 64, NEXP), 256, 0, stream>>>(W2, w2t, FFN, DIM);
    gating_kernel<<<N_TOK / 4, 256, 0, stream>>>(x, Wg, xb, topk_e, topk_w, counts);
    scatter_kernel<<<N_TOK / 256, 256, 0, stream>>>(topk_e, topk_w, counts, offs, cursors, entry_token, entry_pos);
    gemm1_kernel<<<NEXP * MAXM * (FFN / 128), 256, 0, stream>>>(xb, w1t, b1, offs, entry_token, h);
    gemm2_kernel<<<NEXP * MAXM * (DIM / 128), 256, 0, stream>>>(h, w2t, b2, offs, o);
    combine_kernel<<<N_TOK, 256, 0, stream>>>(o, entry_pos, topk_w, y);
}

// Round 4
// 996.029 us; speedup vs baseline: 1.1168x; 1.0522x over previous
//
#include <hip/hip_runtime.h>

#define N_TOK 8192
#define DIM   1024
#define FFN   4096
#define NEXP  8
#define TOPK  2
#define NENT  (N_TOK * TOPK)   // 16384
#define MAXM  20               // max 128-row m-tiles per expert (cnt<=2560; mean 2048, sigma 42)

using short8  = __attribute__((ext_vector_type(8))) short;
using floatx4 = __attribute__((ext_vector_type(4))) float;

__device__ __forceinline__ unsigned short f2bf(float f) {
    union { float f; unsigned u; } v; v.f = f;
    unsigned r = v.u + 0x7fffu + ((v.u >> 16) & 1u);   // round-to-nearest-even
    return (unsigned short)(r >> 16);
}

__device__ __forceinline__ float bf2f(unsigned short s) {
    union { unsigned u; float f; } v; v.u = ((unsigned)s) << 16;
    return v.f;
}

#define GLOAD_LDS16(gptr, lptr) __builtin_amdgcn_global_load_lds( \
    (__attribute__((address_space(1))) void*)(void*)(gptr),       \
    (__attribute__((address_space(3))) void*)(lptr), 16, 0, 0)

// ---------------- conversion kernels ----------------

// in: [E][R][C] f32 -> out: [E][C][R] bf16; 64x64 tiles.
// Loads vectorized to float4 (16 B/lane, G13); writes ushort4.
__global__ __launch_bounds__(256) void transpose_cvt(const float* __restrict__ in,
                                                     unsigned short* __restrict__ out,
                                                     int R, int C) {
    __shared__ float tile[64][65];
    int e  = blockIdx.z;
    int c0 = blockIdx.x * 64;
    int r0 = blockIdx.y * 64;
    const float* inp = in + (size_t)e * R * C;
    unsigned short* outp = out + (size_t)e * R * C;
    int tid = threadIdx.x;
    int lrow = tid >> 4;          // 0..15
    int lc4  = (tid & 15) * 4;    // float4 column
#pragma unroll
    for (int i = 0; i < 4; i++) {
        int r = i * 16 + lrow;
        float4 v = *(const float4*)&inp[(size_t)(r0 + r) * C + c0 + lc4];
        tile[r][lc4 + 0] = v.x;
        tile[r][lc4 + 1] = v.y;
        tile[r][lc4 + 2] = v.z;
        tile[r][lc4 + 3] = v.w;
    }
    __syncthreads();
    int r4 = (tid & 15) * 4;
#pragma unroll
    for (int i = 0; i < 4; i++) {
        int c = i * 16 + (tid >> 4);
        ushort4 o;
        o.x = f2bf(tile[r4 + 0][c]);
        o.y = f2bf(tile[r4 + 1][c]);
        o.z = f2bf(tile[r4 + 2][c]);
        o.w = f2bf(tile[r4 + 3][c]);
        *(ushort4*)&outp[(size_t)(c0 + c) * R + r0 + r4] = o;
    }
}

// ---------------- gating / routing (x->bf16 conversion fused in) ----------------

__global__ __launch_bounds__(256) void gating_kernel(const float* __restrict__ x,
                                                     const float* __restrict__ wg,
                                                     unsigned short* __restrict__ xb,
                                                     int* __restrict__ topk_e,
                                                     float* __restrict__ topk_w,
                                                     int* __restrict__ counts) {
    int wave = threadIdx.x >> 6, lane = threadIdx.x & 63;
    int t = blockIdx.x * 4 + wave;
    const float* xr = x + (size_t)t * DIM;
    unsigned short* xbr = xb + (size_t)t * DIM;
    float acc[NEXP];
#pragma unroll
    for (int e = 0; e < NEXP; e++) acc[e] = 0.f;
    for (int it = 0; it < DIM / 64; it++) {
        int d = it * 64 + lane;
        float xv = xr[d];
        xbr[d] = f2bf(xv);                       // fused bf16 conversion of x
        const float4* wr = (const float4*)(wg + d * NEXP);
        float4 w0 = wr[0], w1 = wr[1];
        acc[0] += xv * w0.x; acc[1] += xv * w0.y; acc[2] += xv * w0.z; acc[3] += xv * w0.w;
        acc[4] += xv * w1.x; acc[5] += xv * w1.y; acc[6] += xv * w1.z; acc[7] += xv * w1.w;
    }
#pragma unroll
    for (int e = 0; e < NEXP; e++) {
#pragma unroll
        for (int off = 32; off > 0; off >>= 1) acc[e] += __shfl_xor(acc[e], off);
    }
    if (lane == 0) {
        int e1 = 0; float l1 = acc[0];
        for (int e = 1; e < NEXP; e++) if (acc[e] > l1) { l1 = acc[e]; e1 = e; }
        int e2 = -1; float l2 = -3.4e38f;
        for (int e = 0; e < NEXP; e++) if (e != e1 && acc[e] > l2) { l2 = acc[e]; e2 = e; }
        float w1v = 1.f / (1.f + expf(l2 - l1));   // softmax top-2 renormalized
        topk_e[t * 2]     = e1;  topk_e[t * 2 + 1] = e2;
        topk_w[t * 2]     = w1v; topk_w[t * 2 + 1] = 1.f - w1v;
        atomicAdd(&counts[e1], 1);
        atomicAdd(&counts[e2], 1);
    }
}

// scatter with the tiny 8-element prefix computed per-thread (prefix_kernel fused)
__global__ __launch_bounds__(256) void scatter_kernel(const int* __restrict__ topk_e,
                                                      const float* __restrict__ topk_w,
                                                      const int* __restrict__ counts,
                                                      int* __restrict__ offs,
                                                      int* __restrict__ cursors,
                                                      int* __restrict__ entry_token,
                                                      int* __restrict__ entry_pos) {
    int off_[NEXP]; int s = 0;
#pragma unroll
    for (int e = 0; e < NEXP; e++) { off_[e] = s; s += counts[e]; }
    if (blockIdx.x == 0 && threadIdx.x == 0) {
#pragma unroll
        for (int e = 0; e < NEXP; e++) offs[e] = off_[e];
        offs[NEXP] = s;
    }
    int t = blockIdx.x * 256 + threadIdx.x;   // grid exact
#pragma unroll
    for (int k = 0; k < TOPK; k++) {
        int e = topk_e[t * 2 + k];
        int pos = off_[e] + atomicAdd(&cursors[e], 1);
        entry_token[pos] = t;
        entry_pos[t * 2 + k] = pos;
    }
}

// ---------------- GEMM1: h = relu(x[tok] @ W1_e + b1_e) ----------------
// 128x128 tile, BK=32, XOR swizzle (2-way = free), double-buffered LDS,
// 3 blocks/CU. XCD-aware bijective block swizzle: groups g=(e,nt) are
// distributed g%8 -> XCD; within an XCD, all m-tiles of one group run
// consecutively so the B panel (0.5 MB) stays L2-resident, and the 4
// consecutive groups sharing an expert re-visit that expert's gathered
// A rows (~4.2 MB <= 4 MB L2) while warm.

__global__ __launch_bounds__(256, 3) void gemm1_kernel(
    const unsigned short* __restrict__ xb,    // [N_TOK][DIM] bf16
    const unsigned short* __restrict__ w1t,   // [E][FFN][DIM] bf16
    const float* __restrict__ b1,             // [E][FFN]
    const int* __restrict__ offs,
    const int* __restrict__ entry_token,
    unsigned short* __restrict__ h)           // [NENT+128][FFN] bf16
{
    int bid   = blockIdx.x;
    int xcd   = bid & 7;
    int inner = bid >> 3;                 // 0 .. 32*MAXM-1
    int gq    = inner / MAXM;             // 0..31
    int mt    = inner - gq * MAXM;        // 0..MAXM-1
    int g     = gq * 8 + xcd;             // group id 0..255
    int e     = g >> 5;                   // 0..7
    int nt    = g & 31;                   // 0..31
    int base = offs[e];
    int cnt  = offs[e + 1] - base;
    int m0   = mt * 128;
    if (m0 >= cnt) return;
    int f0   = nt * 128;

    __shared__ unsigned short As[2][128 * 32];   // 2 x 8 KB
    __shared__ unsigned short Bs[2][128 * 32];
    __shared__ int toks[128];

    int tid = threadIdx.x;
    if (tid < 128) {
        int r = m0 + tid;
        toks[tid] = entry_token[base + (r < cnt ? r : 0)];
    }
    __syncthreads();

    int wave = tid >> 6, lane = tid & 63;
    int wm = (wave >> 1) * 64, wn = (wave & 1) * 64;

    // staging: wave stages rows [wave*32, +32), 2 chunks of 16 rows each
    int lr = lane >> 2, sl = lane & 3;
    int g0 = (sl ^ ((lr >> 1) & 3)) * 8;   // swizzled global slot (shorts)
    const unsigned short* aG[2];
    const unsigned short* bG[2];
    int ldsOff[2];
#pragma unroll
    for (int c = 0; c < 2; c++) {
        int row = wave * 32 + c * 16 + lr;
        aG[c] = xb + (size_t)toks[row] * DIM + g0;
        bG[c] = w1t + ((size_t)e * FFN + f0 + row) * DIM + g0;
        ldsOff[c] = (wave * 32 + c * 16) * 32;
    }

    floatx4 acc[4][4];
#pragma unroll
    for (int i = 0; i < 4; i++)
#pragma unroll
        for (int j = 0; j < 4; j++) acc[i][j] = (floatx4)0.f;

    int quad = lane >> 4, rm = lane & 15;
    int slf  = (quad ^ ((rm >> 1) & 3)) * 8;   // fragment slot (shorts)
    int arow = (wm + rm) * 32;
    int brow = (wn + rm) * 32;

    // prologue: stage tile 0 into buffer 0
#pragma unroll
    for (int c = 0; c < 2; c++) {
        GLOAD_LDS16(aG[c], &As[0][ldsOff[c]]);
        GLOAD_LDS16(bG[c], &Bs[0][ldsOff[c]]);
        aG[c] += 32; bG[c] += 32;
    }

    int cur = 0;
    for (int kk = 0; kk < DIM / 32; kk++) {
        __syncthreads();   // drains prefetch issued last iter; publishes buf[cur]
        short8 af[4], bfr[4];
#pragma unroll
        for (int mi = 0; mi < 4; mi++) af[mi] = *(const short8*)&As[cur][arow + mi * 512 + slf];
#pragma unroll
        for (int ni = 0; ni < 4; ni++) bfr[ni] = *(const short8*)&Bs[cur][brow + ni * 512 + slf];
        if (kk + 1 < DIM / 32) {
            int nxt = cur ^ 1;
#pragma unroll
            for (int c = 0; c < 2; c++) {
                GLOAD_LDS16(aG[c], &As[nxt][ldsOff[c]]);
                GLOAD_LDS16(bG[c], &Bs[nxt][ldsOff[c]]);
                aG[c] += 32; bG[c] += 32;
            }
        }
#pragma unroll
        for (int mi = 0; mi < 4; mi++)
#pragma unroll
            for (int ni = 0; ni < 4; ni++)
                acc[mi][ni] = __builtin_amdgcn_mfma_f32_16x16x32_bf16(af[mi], bfr[ni], acc[mi][ni], 0, 0, 0);
        cur ^= 1;
    }

    // epilogue: D layout col = lane&15, row = quad*4 + r
#pragma unroll
    for (int mi = 0; mi < 4; mi++) {
        int mbase = wm + mi * 16 + quad * 4;
#pragma unroll
        for (int ni = 0; ni < 4; ni++) {
            int f = f0 + wn + ni * 16 + rm;
            float bias = b1[e * FFN + f];
            floatx4 v = acc[mi][ni];
#pragma unroll
            for (int r = 0; r < 4; r++) {
                int row = m0 + mbase + r;
                if (row < cnt) {
                    float t = v[r] + bias;
                    t = t > 0.f ? t : 0.f;
                    h[(size_t)(base + row) * FFN + f] = f2bf(t);
                }
            }
        }
    }
}

// ---------------- GEMM2: o[entry] = h @ W2_e + b2_e (bf16 stores) ----------------
// Round-0 mapping restored: e = bid&7 (expert pinned per XCD), mt fast within
// n-group so the w2t B panel (1 MB) stays L2-resident across ~16-20 m-tiles;
// the 16.8 MB per-expert h slab cannot be L2-resident, its nt-sweep re-reads
// are absorbed by L3 (h = 134 MB < 256 MB). (Round-3's nt-per-XCD mapping made
// every XCD stream all of h: FETCH 732 MB, +25 us — reverted.)

__global__ __launch_bounds__(256, 3) void gemm2_kernel(
    const unsigned short* __restrict__ h,     // [NENT+128][FFN]
    const unsigned short* __restrict__ w2t,   // [E][DIM][FFN]
    const float* __restrict__ b2,             // [E][DIM]
    const int* __restrict__ offs,
    unsigned short* __restrict__ o)           // [NENT+128][DIM] bf16
{
    int bid  = blockIdx.x;
    int e    = bid & 7;
    int grp  = bid % (8 * MAXM);
    int mt   = grp >> 3;               // m fast
    int nt   = bid / (8 * MAXM);       // 0..7 outer
    int base = offs[e];
    int cnt  = offs[e + 1] - base;
    int m0   = mt * 128;
    if (m0 >= cnt) return;
    int n0   = nt * 128;

    __shared__ unsigned short As[2][128 * 32];
    __shared__ unsigned short Bs[2][128 * 32];

    int tid = threadIdx.x;
    int wave = tid >> 6, lane = tid & 63;
    int wm = (wave >> 1) * 64, wn = (wave & 1) * 64;

    int lr = lane >> 2, sl = lane & 3;
    int g0 = (sl ^ ((lr >> 1) & 3)) * 8;
    const unsigned short* aG[2];
    const unsigned short* bG[2];
    int ldsOff[2];
#pragma unroll
    for (int c = 0; c < 2; c++) {
        int row = wave * 32 + c * 16 + lr;
        aG[c] = h + (size_t)(base + m0 + row) * FFN + g0;
        bG[c] = w2t + ((size_t)e * DIM + n0 + row) * FFN + g0;
        ldsOff[c] = (wave * 32 + c * 16) * 32;
    }

    floatx4 acc[4][4];
#pragma unroll
    for (int i = 0; i < 4; i++)
#pragma unroll
        for (int j = 0; j < 4; j++) acc[i][j] = (floatx4)0.f;

    int quad = lane >> 4, rm = lane & 15;
    int slf  = (quad ^ ((rm >> 1) & 3)) * 8;
    int arow = (wm + rm) * 32;
    int brow = (wn + rm) * 32;

#pragma unroll
    for (int c = 0; c < 2; c++) {
        GLOAD_LDS16(aG[c], &As[0][ldsOff[c]]);
        GLOAD_LDS16(bG[c], &Bs[0][ldsOff[c]]);
        aG[c] += 32; bG[c] += 32;
    }

    int cur = 0;
    for (int kk = 0; kk < FFN / 32; kk++) {
        __syncthreads();
        short8 af[4], bfr[4];
#pragma unroll
        for (int mi = 0; mi < 4; mi++) af[mi] = *(const short8*)&As[cur][arow + mi * 512 + slf];
#pragma unroll
        for (int ni = 0; ni < 4; ni++) bfr[ni] = *(const short8*)&Bs[cur][brow + ni * 512 + slf];
        if (kk + 1 < FFN / 32) {
            int nxt = cur ^ 1;
#pragma unroll
            for (int c = 0; c < 2; c++) {
                GLOAD_LDS16(aG[c], &As[nxt][ldsOff[c]]);
                GLOAD_LDS16(bG[c], &Bs[nxt][ldsOff[c]]);
                aG[c] += 32; bG[c] += 32;
            }
        }
#pragma unroll
        for (int mi = 0; mi < 4; mi++)
#pragma unroll
            for (int ni = 0; ni < 4; ni++)
                acc[mi][ni] = __builtin_amdgcn_mfma_f32_16x16x32_bf16(af[mi], bfr[ni], acc[mi][ni], 0, 0, 0);
        cur ^= 1;
    }

#pragma unroll
    for (int mi = 0; mi < 4; mi++) {
        int mbase = wm + mi * 16 + quad * 4;
#pragma unroll
        for (int ni = 0; ni < 4; ni++) {
            int n = n0 + wn + ni * 16 + rm;
            float bias = b2[e * DIM + n];
            floatx4 v = acc[mi][ni];
#pragma unroll
            for (int r = 0; r < 4; r++) {
                int row = m0 + mbase + r;
                if (row < cnt)
                    o[(size_t)(base + row) * DIM + n] = f2bf(v[r] + bias);
            }
        }
    }
}

// ---------------- combine: y[t] = w0*o[p0] + w1*o[p1] ----------------

__global__ __launch_bounds__(256) void combine_kernel(const unsigned short* __restrict__ o,
                                                      const int* __restrict__ entry_pos,
                                                      const float* __restrict__ topk_w,
                                                      float* __restrict__ y) {
    int t = blockIdx.x;
    int d = threadIdx.x * 4;
    int p0 = entry_pos[t * 2], p1 = entry_pos[t * 2 + 1];
    float w0 = topk_w[t * 2], w1 = topk_w[t * 2 + 1];
    ushort4 a = *(const ushort4*)&o[(size_t)p0 * DIM + d];
    ushort4 b = *(const ushort4*)&o[(size_t)p1 * DIM + d];
    float4 r;
    r.x = w0 * bf2f(a.x) + w1 * bf2f(b.x);
    r.y = w0 * bf2f(a.y) + w1 * bf2f(b.y);
    r.z = w0 * bf2f(a.z) + w1 * bf2f(b.z);
    r.w = w0 * bf2f(a.w) + w1 * bf2f(b.w);
    *(float4*)&y[(size_t)t * DIM + d] = r;
}

// ---------------- launch ----------------

extern "C" void kernel_launch(void* const* d_in, const int* in_sizes, int n_in,
                              void* d_out, int out_size, void* d_ws, size_t ws_size,
                              hipStream_t stream) {
    const float* x  = (const float*)d_in[0];
    const float* Wg = (const float*)d_in[1];
    const float* W1 = (const float*)d_in[2];
    const float* b1 = (const float*)d_in[3];
    const float* W2 = (const float*)d_in[4];
    const float* b2 = (const float*)d_in[5];
    float* y = (float*)d_out;

    char* p = (char*)d_ws;
    unsigned short* xb  = (unsigned short*)p; p += (size_t)N_TOK * DIM * 2;          // 16 MB
    unsigned short* w1t = (unsigned short*)p; p += (size_t)NEXP * DIM * FFN * 2;     // 64 MB
    unsigned short* w2t = (unsigned short*)p; p += (size_t)NEXP * DIM * FFN * 2;     // 64 MB
    unsigned short* h   = (unsigned short*)p; p += (size_t)(NENT + 128) * FFN * 2;   // 129 MB
    int*   topk_e      = (int*)p;   p += (size_t)N_TOK * TOPK * 4;
    float* topk_w      = (float*)p; p += (size_t)N_TOK * TOPK * 4;
    int*   entry_token = (int*)p;   p += (size_t)NENT * 4;
    int*   entry_pos   = (int*)p;   p += (size_t)NENT * 4;
    int*   counts      = (int*)p;   p += NEXP * 4;
    int*   cursors     = (int*)p;   p += NEXP * 4;
    int*   offs        = (int*)p;   p += (NEXP + 1) * 4;

    // o overlays w1t: w1t is consumed by gemm1, o is produced by gemm2 (later
    // in stream order). (NENT+128)*DIM*2 = 33.8 MB <= 64 MB.
    unsigned short* o = w1t;

    hipMemsetAsync(counts, 0, NEXP * 4 * 2, stream);   // counts + cursors (adjacent)

    transpose_cvt<<<dim3(FFN / 64, DIM / 64, NEXP), 256, 0, stream>>>(W1, w1t, DIM, FFN);
    transpose_cvt<<<dim3(DIM / 64, FFN / 64, NEXP), 256, 0, stream>>>(W2, w2t, FFN, DIM);
    gating_kernel<<<N_TOK / 4, 256, 0, stream>>>(x, Wg, xb, topk_e, topk_w, counts);
    scatter_kernel<<<N_TOK / 256, 256, 0, stream>>>(topk_e, topk_w, counts, offs, cursors, entry_token, entry_pos);
    gemm1_kernel<<<NEXP * MAXM * (FFN / 128), 256, 0, stream>>>(xb, w1t, b1, offs, entry_token, h);
    gemm2_kernel<<<NEXP * MAXM * (DIM / 128), 256, 0, stream>>>(h, w2t, b2, offs, o);
    combine_kernel<<<N_TOK, 256, 0, stream>>>(o, entry_pos, topk_w, y);
}